// Round 1
// baseline (5204.559 us; speedup 1.0000x reference)
//
#include <hip/hip_runtime.h>

#define UCNT 100000
#define ICNT 50000
#define NN   150000
#define DD   64
#define EE   2000000
#define EPSV 0.2f

// x = concat(user_emb, item_emb), float4-vectorized
__global__ void concat_kernel(const float4* __restrict__ ue,
                              const float4* __restrict__ ie,
                              float4* __restrict__ x) {
    int t = blockIdx.x * blockDim.x + threadIdx.x;
    const int uq = UCNT * DD / 4;
    const int tq = NN * DD / 4;
    if (t >= tq) return;
    x[t] = (t < uq) ? ue[t] : ie[t - uq];
}

// COO SPMM: y[rows[e]] += vals[e] * x[cols[e]]
// 16 lanes per edge; each lane handles 4 dims (float4 gather + 4 atomicAdd)
__global__ void spmm_kernel(const int*   __restrict__ rows,
                            const int*   __restrict__ cols,
                            const float* __restrict__ vals,
                            const float* __restrict__ x,
                            float*       __restrict__ y) {
    long long t = (long long)blockIdx.x * blockDim.x + threadIdx.x;
    int e = (int)(t >> 4);
    int q = (int)(t & 15);
    if (e >= EE) return;
    int r = rows[e];
    int c = cols[e];
    float v = vals[e];
    float4 xv = ((const float4*)(x + (size_t)c * DD))[q];
    float* yr = y + (size_t)r * DD + q * 4;
    atomicAdd(yr + 0, v * xv.x);
    atomicAdd(yr + 1, v * xv.y);
    atomicAdd(yr + 2, v * xv.z);
    atomicAdd(yr + 3, v * xv.w);
}

// Per-row: ego = y + sign(y) * (noise_k / max(||noise_k||,1e-12)) * EPS
// writes ego -> x (next layer input); accumulates into out.
// k==0: out[0:N]=ego, out[N:2N]=ego (cl); k==1: out += ego; k==2: out=(out+ego)/3
__global__ void layer_kernel(const float* __restrict__ y,
                             const float* __restrict__ noise_k,
                             float*       __restrict__ x,
                             float*       __restrict__ out,
                             int k) {
    long long t = (long long)blockIdx.x * blockDim.x + threadIdx.x;
    int r = (int)(t >> 6);
    int d = (int)(t & 63);
    if (r >= NN) return;
    size_t idx = (size_t)r * DD + d;
    float nv = noise_k[idx];
    float ss = nv * nv;
    #pragma unroll
    for (int off = 32; off >= 1; off >>= 1)
        ss += __shfl_xor(ss, off, 64);
    float norm = fmaxf(sqrtf(ss), 1e-12f);
    float yv = y[idx];
    float sg = (yv > 0.0f) ? 1.0f : ((yv < 0.0f) ? -1.0f : 0.0f);
    float ego = yv + sg * (nv / norm) * EPSV;
    x[idx] = ego;
    if (k == 0) {
        out[idx] = ego;
        out[(size_t)NN * DD + idx] = ego;
    } else if (k == 1) {
        out[idx] += ego;
    } else {
        out[idx] = (out[idx] + ego) * (1.0f / 3.0f);
    }
}

extern "C" void kernel_launch(void* const* d_in, const int* in_sizes, int n_in,
                              void* d_out, int out_size, void* d_ws, size_t ws_size,
                              hipStream_t stream) {
    const float* ue    = (const float*)d_in[0];
    const float* ie    = (const float*)d_in[1];
    const int*   erow  = (const int*)  d_in[2];
    const int*   ecol  = (const int*)  d_in[3];
    const float* evals = (const float*)d_in[4];
    const float* noise = (const float*)d_in[5];
    float* out = (float*)d_out;

    float* x = (float*)d_ws;                 // [N, D] current ego
    float* y = x + (size_t)NN * DD;          // [N, D] spmm output

    // 1) x = concat(user, item)
    {
        int tq = NN * DD / 4;
        int blk = 256, grd = (tq + blk - 1) / blk;
        concat_kernel<<<grd, blk, 0, stream>>>((const float4*)ue, (const float4*)ie,
                                               (float4*)x);
    }

    // 2) three propagation layers
    for (int k = 0; k < 3; ++k) {
        hipMemsetAsync(y, 0, (size_t)NN * DD * sizeof(float), stream);

        long long spmm_threads = (long long)EE * 16;
        int blk = 256;
        int grd = (int)((spmm_threads + blk - 1) / blk);
        spmm_kernel<<<grd, blk, 0, stream>>>(erow, ecol, evals, x, y);

        long long row_threads = (long long)NN * DD;
        int grd2 = (int)((row_threads + blk - 1) / blk);
        layer_kernel<<<grd2, blk, 0, stream>>>(y, noise + (size_t)k * NN * DD,
                                               x, out, k);
    }
}

// Round 3
// 685.333 us; speedup vs baseline: 7.5942x; 7.5942x over previous
//
#include <hip/hip_runtime.h>

#define UCNT 100000
#define NN   150000
#define DD   64
#define EE   2000000
#define EPSV 0.2f

#define SCAN_BLK   256
#define SCAN_ELEMS 1024
#define NBLK       ((NN + SCAN_ELEMS - 1) / SCAN_ELEMS)   // 147

// ---- CSR build ----------------------------------------------------------

__global__ void hist_kernel(const int* __restrict__ rows, int* __restrict__ counts) {
    int e = blockIdx.x * blockDim.x + threadIdx.x;
    if (e < EE) atomicAdd(&counts[rows[e]], 1);
}

// per-block exclusive scan (4 elems/thread), emits block sums
__global__ void scanA(const int* __restrict__ counts, int* __restrict__ base,
                      int* __restrict__ bsum) {
    int b = blockIdx.x, t = threadIdx.x;
    int i0 = b * SCAN_ELEMS + t * 4;
    int c0 = (i0 + 0 < NN) ? counts[i0 + 0] : 0;
    int c1 = (i0 + 1 < NN) ? counts[i0 + 1] : 0;
    int c2 = (i0 + 2 < NN) ? counts[i0 + 2] : 0;
    int c3 = (i0 + 3 < NN) ? counts[i0 + 3] : 0;
    int s = c0 + c1 + c2 + c3;
    __shared__ int lds[SCAN_BLK];
    lds[t] = s;
    __syncthreads();
    for (int off = 1; off < SCAN_BLK; off <<= 1) {
        int add = (t >= off) ? lds[t - off] : 0;
        __syncthreads();
        lds[t] += add;
        __syncthreads();
    }
    int excl = lds[t] - s;
    if (i0 + 0 < NN) base[i0 + 0] = excl;
    if (i0 + 1 < NN) base[i0 + 1] = excl + c0;
    if (i0 + 2 < NN) base[i0 + 2] = excl + c0 + c1;
    if (i0 + 3 < NN) base[i0 + 3] = excl + c0 + c1 + c2;
    if (t == SCAN_BLK - 1) bsum[b] = lds[t];
}

// exclusive scan of the (<=256) block sums, single block
__global__ void scanB(int* __restrict__ bsum) {
    int t = threadIdx.x;
    int v = (t < NBLK) ? bsum[t] : 0;
    __shared__ int lds[SCAN_BLK];
    lds[t] = v;
    __syncthreads();
    for (int off = 1; off < SCAN_BLK; off <<= 1) {
        int add = (t >= off) ? lds[t - off] : 0;
        __syncthreads();
        lds[t] += add;
        __syncthreads();
    }
    if (t < NBLK) bsum[t] = lds[t] - v;
}

__global__ void scanC(int* __restrict__ base, const int* __restrict__ bsum) {
    int b = blockIdx.x, t = threadIdx.x;
    int add = bsum[b];
    int i0 = b * SCAN_ELEMS + t * 4;
    if (i0 + 0 < NN) base[i0 + 0] += add;
    if (i0 + 1 < NN) base[i0 + 1] += add;
    if (i0 + 2 < NN) base[i0 + 2] += add;
    if (i0 + 3 < NN) base[i0 + 3] += add;
}

// scatter only the edge id (order within row is non-deterministic here)
__global__ void scatter_kernel(const int* __restrict__ rows,
                               const int* __restrict__ base, int* __restrict__ cursor,
                               int* __restrict__ ceid) {
    int e = blockIdx.x * blockDim.x + threadIdx.x;
    if (e >= EE) return;
    int r = rows[e];
    int pos = base[r] + atomicAdd(&cursor[r], 1);
    ceid[pos] = e;
}

// canonicalize: sort each row segment by edge id (deterministic CSR),
// then fill ccol/cval in that order.
__global__ void rowsort_fill(const int* __restrict__ base, const int* __restrict__ counts,
                             int* __restrict__ ceid,
                             const int* __restrict__ cols, const float* __restrict__ vals,
                             int* __restrict__ ccol, float* __restrict__ cval) {
    int r = blockIdx.x * blockDim.x + threadIdx.x;
    if (r >= NN) return;
    int s = base[r], n = counts[r];
    for (int i = 1; i < n; ++i) {              // insertion sort (avg degree ~13)
        int key = ceid[s + i];
        int j = i - 1;
        while (j >= 0 && ceid[s + j] > key) {
            ceid[s + j + 1] = ceid[s + j];
            --j;
        }
        ceid[s + j + 1] = key;
    }
    for (int i = 0; i < n; ++i) {
        int e = ceid[s + i];
        ccol[s + i] = cols[e];
        cval[s + i] = vals[e];
    }
}

// ---- fused gather-SPMM + noise perturbation + output accumulation -------
// one 64-lane wave per dest row; 4 groups x 16 lanes; group g takes edge
// start+iter*4+g, lane q holds float4 of dims q*4..q*4+3 of the source row.
__device__ __forceinline__ float sgnf(float v) {
    return (v > 0.0f) ? 1.0f : ((v < 0.0f) ? -1.0f : 0.0f);
}

__global__ void spmm_fused(const int* __restrict__ base, const int* __restrict__ counts,
                           const int* __restrict__ ccol, const float* __restrict__ cval,
                           const float* __restrict__ xu, const float* __restrict__ xi,
                           int usplit,
                           const float* __restrict__ noise_k,
                           float* __restrict__ xout,     // ego store (null at k==2)
                           float* __restrict__ outp,     // acc region (out[0:N])
                           int k) {
    int row = blockIdx.x * 4 + (threadIdx.x >> 6);
    if (row >= NN) return;
    int lane = threadIdx.x & 63;
    int g = lane >> 4, q = lane & 15;
    int s = base[row];
    int end = s + counts[row];

    float4 acc = make_float4(0.f, 0.f, 0.f, 0.f);
    for (int j = s + g; j < end; j += 4) {
        int   c = ccol[j];
        float v = cval[j];
        const float* xr = (c < usplit) ? (xu + (size_t)c * DD)
                                       : (xi + (size_t)(c - usplit) * DD);
        float4 xv = ((const float4*)xr)[q];
        acc.x += v * xv.x;
        acc.y += v * xv.y;
        acc.z += v * xv.z;
        acc.w += v * xv.w;
    }
    // reduce the 4 groups (lanes q, q+16, q+32, q+48 hold same dims)
    acc.x += __shfl_xor(acc.x, 16, 64);
    acc.y += __shfl_xor(acc.y, 16, 64);
    acc.z += __shfl_xor(acc.z, 16, 64);
    acc.w += __shfl_xor(acc.w, 16, 64);
    acc.x += __shfl_xor(acc.x, 32, 64);
    acc.y += __shfl_xor(acc.y, 32, 64);
    acc.z += __shfl_xor(acc.z, 32, 64);
    acc.w += __shfl_xor(acc.w, 32, 64);

    if (lane < 16) {
        size_t ro = (size_t)row * DD + q * 4;
        float4 nv = *(const float4*)(noise_k + ro);
        float ss = nv.x * nv.x + nv.y * nv.y + nv.z * nv.z + nv.w * nv.w;
        ss += __shfl_xor(ss, 1, 64);
        ss += __shfl_xor(ss, 2, 64);
        ss += __shfl_xor(ss, 4, 64);
        ss += __shfl_xor(ss, 8, 64);
        float scale = EPSV / fmaxf(sqrtf(ss), 1e-12f);
        float4 ego;
        ego.x = acc.x + sgnf(acc.x) * nv.x * scale;
        ego.y = acc.y + sgnf(acc.y) * nv.y * scale;
        ego.z = acc.z + sgnf(acc.z) * nv.z * scale;
        ego.w = acc.w + sgnf(acc.w) * nv.w * scale;

        if (k == 0) {
            *(float4*)(xout + ro) = ego;      // cl region doubles as next-layer input
            *(float4*)(outp + ro) = ego;      // acc init
        } else if (k == 1) {
            *(float4*)(xout + ro) = ego;
            float4 o = *(const float4*)(outp + ro);
            o.x += ego.x; o.y += ego.y; o.z += ego.z; o.w += ego.w;
            *(float4*)(outp + ro) = o;
        } else {
            float4 o = *(const float4*)(outp + ro);
            const float inv3 = 1.0f / 3.0f;
            o.x = (o.x + ego.x) * inv3;
            o.y = (o.y + ego.y) * inv3;
            o.z = (o.z + ego.z) * inv3;
            o.w = (o.w + ego.w) * inv3;
            *(float4*)(outp + ro) = o;
        }
    }
}

extern "C" void kernel_launch(void* const* d_in, const int* in_sizes, int n_in,
                              void* d_out, int out_size, void* d_ws, size_t ws_size,
                              hipStream_t stream) {
    const float* ue    = (const float*)d_in[0];
    const float* ie    = (const float*)d_in[1];
    const int*   erow  = (const int*)  d_in[2];
    const int*   ecol  = (const int*)  d_in[3];
    const float* evals = (const float*)d_in[4];
    const float* noise = (const float*)d_in[5];
    float* out = (float*)d_out;

    // workspace layout
    char* w = (char*)d_ws;
    float* x_a   = (float*)w;                    w += (size_t)NN * DD * sizeof(float);
    int*   counts= (int*)w;                      w += (size_t)NN * sizeof(int);
    int*   basep = (int*)w;                      w += (size_t)NN * sizeof(int);
    int*   cursor= (int*)w;                      w += (size_t)NN * sizeof(int);
    int*   bsum  = (int*)w;                      w += 256 * sizeof(int);
    int*   ccol  = (int*)w;                      w += (size_t)EE * sizeof(int);
    float* cval  = (float*)w;                    w += (size_t)EE * sizeof(float);
    int*   ceid  = (int*)w;                      w += (size_t)EE * sizeof(int);

    hipMemsetAsync(counts, 0, (size_t)NN * sizeof(int), stream);
    hipMemsetAsync(cursor, 0, (size_t)NN * sizeof(int), stream);

    int blk = 256;
    hist_kernel<<<(EE + blk - 1) / blk, blk, 0, stream>>>(erow, counts);
    scanA<<<NBLK, SCAN_BLK, 0, stream>>>(counts, basep, bsum);
    scanB<<<1, SCAN_BLK, 0, stream>>>(bsum);
    scanC<<<NBLK, SCAN_BLK, 0, stream>>>(basep, bsum);
    scatter_kernel<<<(EE + blk - 1) / blk, blk, 0, stream>>>(erow, basep, cursor, ceid);
    rowsort_fill<<<(NN + blk - 1) / blk, blk, 0, stream>>>(basep, counts, ceid,
                                                           ecol, evals, ccol, cval);

    float* cl = out + (size_t)NN * DD;   // out[N:2N] = cl region
    int grd = (NN + 3) / 4;
    const int IMAX = 0x7FFFFFFF;

    // k=0: gather from split (ue, ie); ego -> cl region AND out[0:N]
    spmm_fused<<<grd, blk, 0, stream>>>(basep, counts, ccol, cval,
                                        ue, ie, UCNT,
                                        noise + (size_t)0 * NN * DD,
                                        cl, out, 0);
    // k=1: gather from cl region; ego -> x_a; out += ego
    spmm_fused<<<grd, blk, 0, stream>>>(basep, counts, ccol, cval,
                                        cl, nullptr, IMAX,
                                        noise + (size_t)1 * NN * DD,
                                        x_a, out, 1);
    // k=2: gather from x_a; out = (out + ego)/3, ego not stored
    spmm_fused<<<grd, blk, 0, stream>>>(basep, counts, ccol, cval,
                                        x_a, nullptr, IMAX,
                                        noise + (size_t)2 * NN * DD,
                                        nullptr, out, 2);
}

// Round 5
// 640.601 us; speedup vs baseline: 8.1245x; 1.0698x over previous
//
#include <hip/hip_runtime.h>

#define UCNT 100000
#define NN   150000
#define DD   64
#define EE   2000000
#define EPSV 0.2f

#define SCAN_BLK   256
#define SCAN_ELEMS 1024
#define NBLK       ((NN + SCAN_ELEMS - 1) / SCAN_ELEMS)   // 147

// ---- CSR build ----------------------------------------------------------

__global__ void hist_kernel(const int* __restrict__ rows, int* __restrict__ counts) {
    int e = blockIdx.x * blockDim.x + threadIdx.x;
    if (e < EE) atomicAdd(&counts[rows[e]], 1);
}

// per-block exclusive scan (4 elems/thread), emits block sums
__global__ void scanA(const int* __restrict__ counts, int* __restrict__ base,
                      int* __restrict__ bsum) {
    int b = blockIdx.x, t = threadIdx.x;
    int i0 = b * SCAN_ELEMS + t * 4;
    int c0 = (i0 + 0 < NN) ? counts[i0 + 0] : 0;
    int c1 = (i0 + 1 < NN) ? counts[i0 + 1] : 0;
    int c2 = (i0 + 2 < NN) ? counts[i0 + 2] : 0;
    int c3 = (i0 + 3 < NN) ? counts[i0 + 3] : 0;
    int s = c0 + c1 + c2 + c3;
    __shared__ int lds[SCAN_BLK];
    lds[t] = s;
    __syncthreads();
    for (int off = 1; off < SCAN_BLK; off <<= 1) {
        int add = (t >= off) ? lds[t - off] : 0;
        __syncthreads();
        lds[t] += add;
        __syncthreads();
    }
    int excl = lds[t] - s;
    if (i0 + 0 < NN) base[i0 + 0] = excl;
    if (i0 + 1 < NN) base[i0 + 1] = excl + c0;
    if (i0 + 2 < NN) base[i0 + 2] = excl + c0 + c1;
    if (i0 + 3 < NN) base[i0 + 3] = excl + c0 + c1 + c2;
    if (t == SCAN_BLK - 1) bsum[b] = lds[t];
}

// exclusive scan of the (<=256) block sums, single block
__global__ void scanB(int* __restrict__ bsum) {
    int t = threadIdx.x;
    int v = (t < NBLK) ? bsum[t] : 0;
    __shared__ int lds[SCAN_BLK];
    lds[t] = v;
    __syncthreads();
    for (int off = 1; off < SCAN_BLK; off <<= 1) {
        int add = (t >= off) ? lds[t - off] : 0;
        __syncthreads();
        lds[t] += add;
        __syncthreads();
    }
    if (t < NBLK) bsum[t] = lds[t] - v;
}

// add block offsets; also zero the scatter cursor (saves a memset dispatch)
__global__ void scanC(int* __restrict__ base, const int* __restrict__ bsum,
                      int* __restrict__ cursor) {
    int b = blockIdx.x, t = threadIdx.x;
    int add = bsum[b];
    int i0 = b * SCAN_ELEMS + t * 4;
    if (i0 + 0 < NN) { base[i0 + 0] += add; cursor[i0 + 0] = 0; }
    if (i0 + 1 < NN) { base[i0 + 1] += add; cursor[i0 + 1] = 0; }
    if (i0 + 2 < NN) { base[i0 + 2] += add; cursor[i0 + 2] = 0; }
    if (i0 + 3 < NN) { base[i0 + 3] += add; cursor[i0 + 3] = 0; }
}

// scatter edge id (arrival order non-deterministic; canonicalized by sorting)
__global__ void scatter_eid(const int* __restrict__ rows,
                            const int* __restrict__ base, int* __restrict__ cursor,
                            unsigned* __restrict__ ceid) {
    int e = blockIdx.x * blockDim.x + threadIdx.x;
    if (e >= EE) return;
    int r = rows[e];
    int pos = base[r] + atomicAdd(&cursor[r], 1);
    ceid[pos] = (unsigned)e;
}

// canonicalize: one 64-lane wave per row; bitonic-sort the row's edge ids
// ascending (matches the reference's per-segment summation order), then
// fill (col, val-bits) pairs coalesced.
__global__ void rowsort_fill(const int* __restrict__ base, const int* __restrict__ counts,
                             unsigned* __restrict__ ceid,
                             const int* __restrict__ cols, const float* __restrict__ vals,
                             int2* __restrict__ cpair) {
    int row = blockIdx.x * 4 + (threadIdx.x >> 6);
    if (row >= NN) return;
    int lane = threadIdx.x & 63;
    int s = base[row], n = counts[row];
    if (n == 0) return;
    if (n <= 64) {
        unsigned key = 0xFFFFFFFFu;                   // pad sorts to the end
        if (lane < n) key = ceid[s + lane];
        #pragma unroll
        for (int k = 2; k <= 64; k <<= 1) {
            #pragma unroll
            for (int j = k >> 1; j > 0; j >>= 1) {
                unsigned other = __shfl_xor(key, j, 64);
                bool up    = ((lane & k) == 0);
                bool lower = ((lane & j) == 0);
                unsigned mn = (key < other) ? key : other;
                unsigned mx = (key < other) ? other : key;
                key = (lower == up) ? mn : mx;
            }
        }
        if (lane < n) {
            int e = (int)key;
            cpair[s + lane] = make_int2(cols[e], __float_as_int(vals[e]));
        }
    } else if (lane == 0) {                           // ~never (Poisson mean 13)
        for (int i = 1; i < n; ++i) {
            unsigned kk = ceid[s + i];
            int j = i - 1;
            while (j >= 0 && ceid[s + j] > kk) {
                ceid[s + j + 1] = ceid[s + j];
                --j;
            }
            ceid[s + j + 1] = kk;
        }
        for (int i = 0; i < n; ++i) {
            int e = (int)ceid[s + i];
            cpair[s + i] = make_int2(cols[e], __float_as_int(vals[e]));
        }
    }
}

// ---- fused gather-SPMM + noise perturbation + output accumulation -------
// one 64-lane wave per dest row; 4 groups x 16 lanes; group g takes edge
// start+iter*4+g, lane q holds float4 of dims q*4..q*4+3 of the source row.
__device__ __forceinline__ float sgnf(float v) {
    return (v > 0.0f) ? 1.0f : ((v < 0.0f) ? -1.0f : 0.0f);
}

__global__ void spmm_fused(const int* __restrict__ base, const int* __restrict__ counts,
                           const int2* __restrict__ cpair,
                           const float* __restrict__ xu, const float* __restrict__ xi,
                           int usplit,
                           const float* __restrict__ noise_k,
                           float* __restrict__ xout,     // ego store (null at k==2)
                           float* __restrict__ outp,     // acc region (out[0:N])
                           int k) {
    int row = blockIdx.x * 4 + (threadIdx.x >> 6);
    if (row >= NN) return;
    int lane = threadIdx.x & 63;
    int g = lane >> 4, q = lane & 15;
    int s = base[row];
    int end = s + counts[row];

    float4 acc = make_float4(0.f, 0.f, 0.f, 0.f);
    for (int j = s + g; j < end; j += 4) {
        int2  p = cpair[j];
        int   c = p.x;
        float v = __int_as_float(p.y);
        const float* xr = (c < usplit) ? (xu + (size_t)c * DD)
                                       : (xi + (size_t)(c - usplit) * DD);
        float4 xv = ((const float4*)xr)[q];
        acc.x += v * xv.x;
        acc.y += v * xv.y;
        acc.z += v * xv.z;
        acc.w += v * xv.w;
    }
    // reduce the 4 groups (lanes q, q+16, q+32, q+48 hold same dims)
    acc.x += __shfl_xor(acc.x, 16, 64);
    acc.y += __shfl_xor(acc.y, 16, 64);
    acc.z += __shfl_xor(acc.z, 16, 64);
    acc.w += __shfl_xor(acc.w, 16, 64);
    acc.x += __shfl_xor(acc.x, 32, 64);
    acc.y += __shfl_xor(acc.y, 32, 64);
    acc.z += __shfl_xor(acc.z, 32, 64);
    acc.w += __shfl_xor(acc.w, 32, 64);

    if (lane < 16) {
        size_t ro = (size_t)row * DD + q * 4;
        float4 nv = *(const float4*)(noise_k + ro);
        float ss = nv.x * nv.x + nv.y * nv.y + nv.z * nv.z + nv.w * nv.w;
        ss += __shfl_xor(ss, 1, 64);
        ss += __shfl_xor(ss, 2, 64);
        ss += __shfl_xor(ss, 4, 64);
        ss += __shfl_xor(ss, 8, 64);
        float scale = EPSV / fmaxf(sqrtf(ss), 1e-12f);
        float4 ego;
        ego.x = acc.x + sgnf(acc.x) * nv.x * scale;
        ego.y = acc.y + sgnf(acc.y) * nv.y * scale;
        ego.z = acc.z + sgnf(acc.z) * nv.z * scale;
        ego.w = acc.w + sgnf(acc.w) * nv.w * scale;

        if (k == 0) {
            *(float4*)(xout + ro) = ego;      // cl region doubles as next-layer input
            *(float4*)(outp + ro) = ego;      // acc init
        } else if (k == 1) {
            *(float4*)(xout + ro) = ego;
            float4 o = *(const float4*)(outp + ro);
            o.x += ego.x; o.y += ego.y; o.z += ego.z; o.w += ego.w;
            *(float4*)(outp + ro) = o;
        } else {
            float4 o = *(const float4*)(outp + ro);
            const float inv3 = 1.0f / 3.0f;
            o.x = (o.x + ego.x) * inv3;
            o.y = (o.y + ego.y) * inv3;
            o.z = (o.z + ego.z) * inv3;
            o.w = (o.w + ego.w) * inv3;
            *(float4*)(outp + ro) = o;
        }
    }
}

extern "C" void kernel_launch(void* const* d_in, const int* in_sizes, int n_in,
                              void* d_out, int out_size, void* d_ws, size_t ws_size,
                              hipStream_t stream) {
    const float* ue    = (const float*)d_in[0];
    const float* ie    = (const float*)d_in[1];
    const int*   erow  = (const int*)  d_in[2];
    const int*   ecol  = (const int*)  d_in[3];
    const float* evals = (const float*)d_in[4];
    const float* noise = (const float*)d_in[5];
    float* out = (float*)d_out;

    // workspace layout
    char* w = (char*)d_ws;
    float* x_a   = (float*)w;                    w += (size_t)NN * DD * sizeof(float);
    int*   counts= (int*)w;                      w += (size_t)NN * sizeof(int);
    int*   basep = (int*)w;                      w += (size_t)NN * sizeof(int);
    int*   cursor= (int*)w;                      w += (size_t)NN * sizeof(int);
    int*   bsum  = (int*)w;                      w += 256 * sizeof(int);
    int2*  cpair = (int2*)w;                     w += (size_t)EE * sizeof(int2);
    unsigned* ceid = (unsigned*)w;               w += (size_t)EE * sizeof(unsigned);

    hipMemsetAsync(counts, 0, (size_t)NN * sizeof(int), stream);

    int blk = 256;
    hist_kernel<<<(EE + blk - 1) / blk, blk, 0, stream>>>(erow, counts);
    scanA<<<NBLK, SCAN_BLK, 0, stream>>>(counts, basep, bsum);
    scanB<<<1, SCAN_BLK, 0, stream>>>(bsum);
    scanC<<<NBLK, SCAN_BLK, 0, stream>>>(basep, bsum, cursor);
    scatter_eid<<<(EE + blk - 1) / blk, blk, 0, stream>>>(erow, basep, cursor, ceid);
    rowsort_fill<<<(NN + 3) / 4, blk, 0, stream>>>(basep, counts, ceid,
                                                   ecol, evals, cpair);

    float* cl = out + (size_t)NN * DD;   // out[N:2N] = cl region
    int grd = (NN + 3) / 4;
    const int IMAX = 0x7FFFFFFF;

    // k=0: gather from split (ue, ie); ego -> cl region AND out[0:N]
    spmm_fused<<<grd, blk, 0, stream>>>(basep, counts, cpair,
                                        ue, ie, UCNT,
                                        noise + (size_t)0 * NN * DD,
                                        cl, out, 0);
    // k=1: gather from cl region; ego -> x_a; out += ego
    spmm_fused<<<grd, blk, 0, stream>>>(basep, counts, cpair,
                                        cl, nullptr, IMAX,
                                        noise + (size_t)1 * NN * DD,
                                        x_a, out, 1);
    // k=2: gather from x_a; out = (out + ego)/3, ego not stored
    spmm_fused<<<grd, blk, 0, stream>>>(basep, counts, cpair,
                                        x_a, nullptr, IMAX,
                                        noise + (size_t)2 * NN * DD,
                                        nullptr, out, 2);
}

// Round 7
// 569.991 us; speedup vs baseline: 9.1309x; 1.1239x over previous
//
#include <hip/hip_runtime.h>

#define UCNT 100000
#define NN   150000
#define DD   64
#define EE   2000000
#define EPSV 0.2f

#define SCAN_BLK   256
#define SCAN_ELEMS 1024
#define NBLK       ((NN + SCAN_ELEMS - 1) / SCAN_ELEMS)   // 147

// ---- CSR build ----------------------------------------------------------

__global__ void hist_kernel(const int* __restrict__ rows, int* __restrict__ counts) {
    int e = blockIdx.x * blockDim.x + threadIdx.x;
    if (e < EE) atomicAdd(&counts[rows[e]], 1);
}

// per-block exclusive scan (4 elems/thread), emits block sums
__global__ void scanA(const int* __restrict__ counts, int* __restrict__ base,
                      int* __restrict__ bsum) {
    int b = blockIdx.x, t = threadIdx.x;
    int i0 = b * SCAN_ELEMS + t * 4;
    int c0 = (i0 + 0 < NN) ? counts[i0 + 0] : 0;
    int c1 = (i0 + 1 < NN) ? counts[i0 + 1] : 0;
    int c2 = (i0 + 2 < NN) ? counts[i0 + 2] : 0;
    int c3 = (i0 + 3 < NN) ? counts[i0 + 3] : 0;
    int s = c0 + c1 + c2 + c3;
    __shared__ int lds[SCAN_BLK];
    lds[t] = s;
    __syncthreads();
    for (int off = 1; off < SCAN_BLK; off <<= 1) {
        int add = (t >= off) ? lds[t - off] : 0;
        __syncthreads();
        lds[t] += add;
        __syncthreads();
    }
    int excl = lds[t] - s;
    if (i0 + 0 < NN) base[i0 + 0] = excl;
    if (i0 + 1 < NN) base[i0 + 1] = excl + c0;
    if (i0 + 2 < NN) base[i0 + 2] = excl + c0 + c1;
    if (i0 + 3 < NN) base[i0 + 3] = excl + c0 + c1 + c2;
    if (t == SCAN_BLK - 1) bsum[b] = lds[t];
}

// exclusive scan of the (<=256) block sums, single block
__global__ void scanB(int* __restrict__ bsum) {
    int t = threadIdx.x;
    int v = (t < NBLK) ? bsum[t] : 0;
    __shared__ int lds[SCAN_BLK];
    lds[t] = v;
    __syncthreads();
    for (int off = 1; off < SCAN_BLK; off <<= 1) {
        int add = (t >= off) ? lds[t - off] : 0;
        __syncthreads();
        lds[t] += add;
        __syncthreads();
    }
    if (t < NBLK) bsum[t] = lds[t] - v;
}

// add block offsets; also zero the scatter cursor (saves a memset dispatch)
__global__ void scanC(int* __restrict__ base, const int* __restrict__ bsum,
                      int* __restrict__ cursor) {
    int b = blockIdx.x, t = threadIdx.x;
    int add = bsum[b];
    int i0 = b * SCAN_ELEMS + t * 4;
    if (i0 + 0 < NN) { base[i0 + 0] += add; cursor[i0 + 0] = 0; }
    if (i0 + 1 < NN) { base[i0 + 1] += add; cursor[i0 + 1] = 0; }
    if (i0 + 2 < NN) { base[i0 + 2] += add; cursor[i0 + 2] = 0; }
    if (i0 + 3 < NN) { base[i0 + 3] += add; cursor[i0 + 3] = 0; }
}

// scatter edge id (arrival order non-deterministic; canonicalized by sorting)
// plain store — nontemporal variant corrupted consumer reads (round 6)
__global__ void scatter_eid(const int* __restrict__ rows,
                            const int* __restrict__ base, int* __restrict__ cursor,
                            unsigned* __restrict__ ceid) {
    int e = blockIdx.x * blockDim.x + threadIdx.x;
    if (e >= EE) return;
    int r = rows[e];
    int pos = base[r] + atomicAdd(&cursor[r], 1);
    ceid[pos] = (unsigned)e;
}

// canonicalize: one 64-lane wave per row; full 64-wide bitonic sort of the
// row's edge ids ascending (round-5-proven), then fill (col, val-bits)
// pairs coalesced.
__global__ void rowsort_fill(const int* __restrict__ base, const int* __restrict__ counts,
                             unsigned* __restrict__ ceid,
                             const int* __restrict__ cols, const float* __restrict__ vals,
                             int2* __restrict__ cpair) {
    int row = blockIdx.x * 4 + (threadIdx.x >> 6);
    if (row >= NN) return;
    int lane = threadIdx.x & 63;
    int s = base[row], n = counts[row];
    if (n == 0) return;
    if (n <= 64) {
        unsigned key = 0xFFFFFFFFu;                   // pad sorts to the end
        if (lane < n) key = ceid[s + lane];
        #pragma unroll
        for (int k = 2; k <= 64; k <<= 1) {
            #pragma unroll
            for (int j = k >> 1; j > 0; j >>= 1) {
                unsigned other = __shfl_xor(key, j, 64);
                bool up    = ((lane & k) == 0);
                bool lower = ((lane & j) == 0);
                unsigned mn = (key < other) ? key : other;
                unsigned mx = (key < other) ? other : key;
                key = (lower == up) ? mn : mx;
            }
        }
        if (lane < n) {
            int e = (int)key;
            cpair[s + lane] = make_int2(cols[e], __float_as_int(vals[e]));
        }
    } else if (lane == 0) {                           // ~never (Poisson mean 13)
        for (int i = 1; i < n; ++i) {
            unsigned kk = ceid[s + i];
            int j = i - 1;
            while (j >= 0 && ceid[s + j] > kk) {
                ceid[s + j + 1] = ceid[s + j];
                --j;
            }
            ceid[s + j + 1] = kk;
        }
        for (int i = 0; i < n; ++i) {
            int e = (int)ceid[s + i];
            cpair[s + i] = make_int2(cols[e], __float_as_int(vals[e]));
        }
    }
}

// ---- fused gather-SPMM + noise perturbation + output accumulation -------
// one 64-lane wave per dest row; 4 groups x 16 lanes. The row's CSR segment
// is loaded with ONE coalesced wave-wide load, then (col,val) broadcast per
// edge via shfl. The broadcast loop trip count is WAVE-UNIFORM (iters =
// ceil(n/4)) so every shfl executes with all 64 lanes active and a clamped
// uniform source index; only the gather+FMA is predicated. Summation index
// order identical to round 5: group g sums edges g, g+4, ... then
// xor16/xor32 reduce.
__device__ __forceinline__ float sgnf(float v) {
    return (v > 0.0f) ? 1.0f : ((v < 0.0f) ? -1.0f : 0.0f);
}

__global__ void spmm_fused(const int* __restrict__ base, const int* __restrict__ counts,
                           const int2* __restrict__ cpair,
                           const float* __restrict__ xu, const float* __restrict__ xi,
                           int usplit,
                           const float* __restrict__ noise_k,
                           float* __restrict__ xout,     // ego store (null at k==2)
                           float* __restrict__ outp,     // acc region (out[0:N])
                           int k) {
    int row = blockIdx.x * 4 + (threadIdx.x >> 6);
    if (row >= NN) return;
    int lane = threadIdx.x & 63;
    int g = lane >> 4, q = lane & 15;
    int s = base[row];
    int n = counts[row];

    // hoisted independent loads (used only by lanes < 16 in the epilogue)
    size_t ro = (size_t)row * DD + q * 4;
    float4 nv    = make_float4(0.f, 0.f, 0.f, 0.f);
    float4 oprev = make_float4(0.f, 0.f, 0.f, 0.f);
    if (lane < 16) {
        nv = *(const float4*)(noise_k + ro);
        if (k != 0) oprev = *(const float4*)(outp + ro);
    }

    float4 acc = make_float4(0.f, 0.f, 0.f, 0.f);
    if (n <= 64) {
        int cx = 0; float vf = 0.f;
        if (lane < n) {
            int2 p = cpair[s + lane];          // one coalesced segment load
            cx = p.x; vf = __int_as_float(p.y);
        }
        int iters = (n + 3) >> 2;              // wave-uniform (n uniform per wave)
        for (int it = 0; it < iters; ++it) {
            int i = g + it * 4;
            int src = (i < n) ? i : (n - 1);   // clamp; uniform-per-group lane id
            int   c = __shfl(cx, src, 64);
            float v = __shfl(vf, src, 64);
            if (i < n) {
                const float* xr = (c < usplit) ? (xu + (size_t)c * DD)
                                               : (xi + (size_t)(c - usplit) * DD);
                float4 xv = ((const float4*)xr)[q];
                acc.x += v * xv.x;
                acc.y += v * xv.y;
                acc.z += v * xv.z;
                acc.w += v * xv.w;
            }
        }
    } else {                                    // ~never (Poisson mean 13)
        for (int j = s + g; j < s + n; j += 4) {
            int2  p = cpair[j];
            int   c = p.x;
            float v = __int_as_float(p.y);
            const float* xr = (c < usplit) ? (xu + (size_t)c * DD)
                                           : (xi + (size_t)(c - usplit) * DD);
            float4 xv = ((const float4*)xr)[q];
            acc.x += v * xv.x;
            acc.y += v * xv.y;
            acc.z += v * xv.z;
            acc.w += v * xv.w;
        }
    }
    // reduce the 4 groups (lanes q, q+16, q+32, q+48 hold same dims)
    acc.x += __shfl_xor(acc.x, 16, 64);
    acc.y += __shfl_xor(acc.y, 16, 64);
    acc.z += __shfl_xor(acc.z, 16, 64);
    acc.w += __shfl_xor(acc.w, 16, 64);
    acc.x += __shfl_xor(acc.x, 32, 64);
    acc.y += __shfl_xor(acc.y, 32, 64);
    acc.z += __shfl_xor(acc.z, 32, 64);
    acc.w += __shfl_xor(acc.w, 32, 64);

    if (lane < 16) {
        float ss = nv.x * nv.x + nv.y * nv.y + nv.z * nv.z + nv.w * nv.w;
        ss += __shfl_xor(ss, 1, 64);
        ss += __shfl_xor(ss, 2, 64);
        ss += __shfl_xor(ss, 4, 64);
        ss += __shfl_xor(ss, 8, 64);
        float scale = EPSV / fmaxf(sqrtf(ss), 1e-12f);
        float4 ego;
        ego.x = acc.x + sgnf(acc.x) * nv.x * scale;
        ego.y = acc.y + sgnf(acc.y) * nv.y * scale;
        ego.z = acc.z + sgnf(acc.z) * nv.z * scale;
        ego.w = acc.w + sgnf(acc.w) * nv.w * scale;

        if (k == 0) {
            *(float4*)(xout + ro) = ego;      // cl region doubles as next-layer input
            *(float4*)(outp + ro) = ego;      // acc init
        } else if (k == 1) {
            *(float4*)(xout + ro) = ego;
            oprev.x += ego.x; oprev.y += ego.y; oprev.z += ego.z; oprev.w += ego.w;
            *(float4*)(outp + ro) = oprev;
        } else {
            const float inv3 = 1.0f / 3.0f;
            float4 o;
            o.x = (oprev.x + ego.x) * inv3;
            o.y = (oprev.y + ego.y) * inv3;
            o.z = (oprev.z + ego.z) * inv3;
            o.w = (oprev.w + ego.w) * inv3;
            *(float4*)(outp + ro) = o;
        }
    }
}

extern "C" void kernel_launch(void* const* d_in, const int* in_sizes, int n_in,
                              void* d_out, int out_size, void* d_ws, size_t ws_size,
                              hipStream_t stream) {
    const float* ue    = (const float*)d_in[0];
    const float* ie    = (const float*)d_in[1];
    const int*   erow  = (const int*)  d_in[2];
    const int*   ecol  = (const int*)  d_in[3];
    const float* evals = (const float*)d_in[4];
    const float* noise = (const float*)d_in[5];
    float* out = (float*)d_out;

    // workspace layout
    char* w = (char*)d_ws;
    float* x_a   = (float*)w;                    w += (size_t)NN * DD * sizeof(float);
    int*   counts= (int*)w;                      w += (size_t)NN * sizeof(int);
    int*   basep = (int*)w;                      w += (size_t)NN * sizeof(int);
    int*   cursor= (int*)w;                      w += (size_t)NN * sizeof(int);
    int*   bsum  = (int*)w;                      w += 256 * sizeof(int);
    int2*  cpair = (int2*)w;                     w += (size_t)EE * sizeof(int2);
    unsigned* ceid = (unsigned*)w;               w += (size_t)EE * sizeof(unsigned);

    hipMemsetAsync(counts, 0, (size_t)NN * sizeof(int), stream);

    int blk = 256;
    hist_kernel<<<(EE + blk - 1) / blk, blk, 0, stream>>>(erow, counts);
    scanA<<<NBLK, SCAN_BLK, 0, stream>>>(counts, basep, bsum);
    scanB<<<1, SCAN_BLK, 0, stream>>>(bsum);
    scanC<<<NBLK, SCAN_BLK, 0, stream>>>(basep, bsum, cursor);
    scatter_eid<<<(EE + blk - 1) / blk, blk, 0, stream>>>(erow, basep, cursor, ceid);
    rowsort_fill<<<(NN + 3) / 4, blk, 0, stream>>>(basep, counts, ceid,
                                                   ecol, evals, cpair);

    float* cl = out + (size_t)NN * DD;   // out[N:2N] = cl region
    int grd = (NN + 3) / 4;
    const int IMAX = 0x7FFFFFFF;

    // k=0: gather from split (ue, ie); ego -> cl region AND out[0:N]
    spmm_fused<<<grd, blk, 0, stream>>>(basep, counts, cpair,
                                        ue, ie, UCNT,
                                        noise + (size_t)0 * NN * DD,
                                        cl, out, 0);
    // k=1: gather from cl region; ego -> x_a; out += ego
    spmm_fused<<<grd, blk, 0, stream>>>(basep, counts, cpair,
                                        cl, nullptr, IMAX,
                                        noise + (size_t)1 * NN * DD,
                                        x_a, out, 1);
    // k=2: gather from x_a; out = (out + ego)/3, ego not stored
    spmm_fused<<<grd, blk, 0, stream>>>(basep, counts, cpair,
                                        x_a, nullptr, IMAX,
                                        noise + (size_t)2 * NN * DD,
                                        nullptr, out, 2);
}

// Round 8
// 559.570 us; speedup vs baseline: 9.3010x; 1.0186x over previous
//
#include <hip/hip_runtime.h>

#define UCNT 100000
#define NN   150000
#define DD   64
#define EE   2000000
#define EPSV 0.2f

#define SCAN_BLK   256
#define SCAN_ELEMS 1024
#define NBLK       ((NN + SCAN_ELEMS - 1) / SCAN_ELEMS)   // 147

// ---- CSR build ----------------------------------------------------------

__global__ void hist_kernel(const int* __restrict__ rows, int* __restrict__ counts) {
    int e = blockIdx.x * blockDim.x + threadIdx.x;
    if (e < EE) atomicAdd(&counts[rows[e]], 1);
}

// per-block exclusive scan (4 elems/thread), emits block sums
__global__ void scanA(const int* __restrict__ counts, int* __restrict__ base,
                      int* __restrict__ bsum) {
    int b = blockIdx.x, t = threadIdx.x;
    int i0 = b * SCAN_ELEMS + t * 4;
    int c0 = (i0 + 0 < NN) ? counts[i0 + 0] : 0;
    int c1 = (i0 + 1 < NN) ? counts[i0 + 1] : 0;
    int c2 = (i0 + 2 < NN) ? counts[i0 + 2] : 0;
    int c3 = (i0 + 3 < NN) ? counts[i0 + 3] : 0;
    int s = c0 + c1 + c2 + c3;
    __shared__ int lds[SCAN_BLK];
    lds[t] = s;
    __syncthreads();
    for (int off = 1; off < SCAN_BLK; off <<= 1) {
        int add = (t >= off) ? lds[t - off] : 0;
        __syncthreads();
        lds[t] += add;
        __syncthreads();
    }
    int excl = lds[t] - s;
    if (i0 + 0 < NN) base[i0 + 0] = excl;
    if (i0 + 1 < NN) base[i0 + 1] = excl + c0;
    if (i0 + 2 < NN) base[i0 + 2] = excl + c0 + c1;
    if (i0 + 3 < NN) base[i0 + 3] = excl + c0 + c1 + c2;
    if (t == SCAN_BLK - 1) bsum[b] = lds[t];
}

// exclusive scan of the (<=256) block sums, single block
__global__ void scanB(int* __restrict__ bsum) {
    int t = threadIdx.x;
    int v = (t < NBLK) ? bsum[t] : 0;
    __shared__ int lds[SCAN_BLK];
    lds[t] = v;
    __syncthreads();
    for (int off = 1; off < SCAN_BLK; off <<= 1) {
        int add = (t >= off) ? lds[t - off] : 0;
        __syncthreads();
        lds[t] += add;
        __syncthreads();
    }
    if (t < NBLK) bsum[t] = lds[t] - v;
}

// add block offsets; also zero the scatter cursor (saves a memset dispatch)
__global__ void scanC(int* __restrict__ base, const int* __restrict__ bsum,
                      int* __restrict__ cursor) {
    int b = blockIdx.x, t = threadIdx.x;
    int add = bsum[b];
    int i0 = b * SCAN_ELEMS + t * 4;
    if (i0 + 0 < NN) { base[i0 + 0] += add; cursor[i0 + 0] = 0; }
    if (i0 + 1 < NN) { base[i0 + 1] += add; cursor[i0 + 1] = 0; }
    if (i0 + 2 < NN) { base[i0 + 2] += add; cursor[i0 + 2] = 0; }
    if (i0 + 3 < NN) { base[i0 + 3] += add; cursor[i0 + 3] = 0; }
}

// scatter edge id (arrival order non-deterministic; canonicalized by sorting)
__global__ void scatter_eid(const int* __restrict__ rows,
                            const int* __restrict__ base, int* __restrict__ cursor,
                            unsigned* __restrict__ ceid) {
    int e = blockIdx.x * blockDim.x + threadIdx.x;
    if (e >= EE) return;
    int r = rows[e];
    int pos = base[r] + atomicAdd(&cursor[r], 1);
    ceid[pos] = (unsigned)e;
}

// canonicalize: one 64-lane wave per row; full 64-wide bitonic sort of the
// row's edge ids ascending, then fill (col, val-bits) pairs coalesced.
__global__ void rowsort_fill(const int* __restrict__ base, const int* __restrict__ counts,
                             unsigned* __restrict__ ceid,
                             const int* __restrict__ cols, const float* __restrict__ vals,
                             int2* __restrict__ cpair) {
    int row = blockIdx.x * 4 + (threadIdx.x >> 6);
    if (row >= NN) return;
    int lane = threadIdx.x & 63;
    int s = base[row], n = counts[row];
    if (n == 0) return;
    if (n <= 64) {
        unsigned key = 0xFFFFFFFFu;                   // pad sorts to the end
        if (lane < n) key = ceid[s + lane];
        #pragma unroll
        for (int k = 2; k <= 64; k <<= 1) {
            #pragma unroll
            for (int j = k >> 1; j > 0; j >>= 1) {
                unsigned other = __shfl_xor(key, j, 64);
                bool up    = ((lane & k) == 0);
                bool lower = ((lane & j) == 0);
                unsigned mn = (key < other) ? key : other;
                unsigned mx = (key < other) ? other : key;
                key = (lower == up) ? mn : mx;
            }
        }
        if (lane < n) {
            int e = (int)key;
            cpair[s + lane] = make_int2(cols[e], __float_as_int(vals[e]));
        }
    } else if (lane == 0) {                           // ~never (Poisson mean 13)
        for (int i = 1; i < n; ++i) {
            unsigned kk = ceid[s + i];
            int j = i - 1;
            while (j >= 0 && ceid[s + j] > kk) {
                ceid[s + j + 1] = ceid[s + j];
                --j;
            }
            ceid[s + j + 1] = kk;
        }
        for (int i = 0; i < n; ++i) {
            int e = (int)ceid[s + i];
            cpair[s + i] = make_int2(cols[e], __float_as_int(vals[e]));
        }
    }
}

// ---- fused gather-SPMM + noise perturbation + output accumulation -------
// 16 lanes per row, 4 rows per wave, 16 rows per block. Each group walks
// its row's edges strictly in sorted-eid order: chunks of 16 (col,val)
// pairs preloaded coalesced, broadcast within the group via shfl (sources
// always inside the caller's own active 16-lane group). Lane q owns dims
// q*4..q*4+3 -> per-element summation order is exactly e0<e1<...
// Epilogue is lane-dense (no cross-group reduce, no masked lanes).
// k==0: ego -> xout(=cl). k==1: ego -> xout(=x_a).
// k==2: outp(=out[0:N]) = (cl_in + xa_in + ego) / 3.
__device__ __forceinline__ float sgnf(float v) {
    return (v > 0.0f) ? 1.0f : ((v < 0.0f) ? -1.0f : 0.0f);
}

__global__ __launch_bounds__(256) void
spmm_fused(const int* __restrict__ base, const int* __restrict__ counts,
           const int2* __restrict__ cpair,
           const float* __restrict__ xu, const float* __restrict__ xi,
           int usplit,
           const float* __restrict__ noise_k,
           float* __restrict__ xout,
           const float* __restrict__ cl_in,
           const float* __restrict__ xa_in,
           float* __restrict__ outp,
           int k) {
    int tid = blockIdx.x * 256 + threadIdx.x;
    int row = tid >> 4;                   // 16 lanes per row
    if (row >= NN) return;
    int lane = threadIdx.x & 63;
    int q  = lane & 15;                   // dim quad within row
    int gb = lane & 48;                   // group base lane within wave

    int s = base[row];
    int n = counts[row];

    // hoisted independent loads
    size_t ro = (size_t)row * DD + q * 4;
    float4 nv = *(const float4*)(noise_k + ro);
    float4 clv = make_float4(0.f, 0.f, 0.f, 0.f);
    float4 xav = make_float4(0.f, 0.f, 0.f, 0.f);
    if (k == 2) {
        clv = *(const float4*)(cl_in + ro);
        xav = *(const float4*)(xa_in + ro);
    }

    float4 acc = make_float4(0.f, 0.f, 0.f, 0.f);
    for (int chunk = 0; chunk < n; chunk += 16) {      // group-uniform bound
        int rem = n - chunk;
        int2 p = make_int2(0, 0);
        if (q < rem) p = cpair[s + chunk + q];         // coalesced 128B/row
        int m = (rem < 16) ? rem : 16;
        for (int i = 0; i < m; ++i) {                  // group-uniform bound
            int   c = __shfl(p.x, gb + i, 64);
            float v = __int_as_float(__shfl(p.y, gb + i, 64));
            const float* xr = (c < usplit) ? (xu + (size_t)c * DD)
                                           : (xi + (size_t)(c - usplit) * DD);
            float4 xv = ((const float4*)xr)[q];
            acc.x += v * xv.x;
            acc.y += v * xv.y;
            acc.z += v * xv.z;
            acc.w += v * xv.w;
        }
    }

    // noise L2 norm within the 16-lane group (xor 1,2,4,8 stays in-group)
    float ss = nv.x * nv.x + nv.y * nv.y + nv.z * nv.z + nv.w * nv.w;
    ss += __shfl_xor(ss, 1, 64);
    ss += __shfl_xor(ss, 2, 64);
    ss += __shfl_xor(ss, 4, 64);
    ss += __shfl_xor(ss, 8, 64);
    float scale = EPSV / fmaxf(sqrtf(ss), 1e-12f);

    float4 ego;
    ego.x = acc.x + sgnf(acc.x) * nv.x * scale;
    ego.y = acc.y + sgnf(acc.y) * nv.y * scale;
    ego.z = acc.z + sgnf(acc.z) * nv.z * scale;
    ego.w = acc.w + sgnf(acc.w) * nv.w * scale;

    if (k == 2) {
        const float inv3 = 1.0f / 3.0f;
        float4 o;
        o.x = (clv.x + xav.x + ego.x) * inv3;
        o.y = (clv.y + xav.y + ego.y) * inv3;
        o.z = (clv.z + xav.z + ego.z) * inv3;
        o.w = (clv.w + xav.w + ego.w) * inv3;
        *(float4*)(outp + ro) = o;
    } else {
        *(float4*)(xout + ro) = ego;
    }
}

extern "C" void kernel_launch(void* const* d_in, const int* in_sizes, int n_in,
                              void* d_out, int out_size, void* d_ws, size_t ws_size,
                              hipStream_t stream) {
    const float* ue    = (const float*)d_in[0];
    const float* ie    = (const float*)d_in[1];
    const int*   erow  = (const int*)  d_in[2];
    const int*   ecol  = (const int*)  d_in[3];
    const float* evals = (const float*)d_in[4];
    const float* noise = (const float*)d_in[5];
    float* out = (float*)d_out;

    // workspace layout
    char* w = (char*)d_ws;
    float* x_a   = (float*)w;                    w += (size_t)NN * DD * sizeof(float);
    int*   counts= (int*)w;                      w += (size_t)NN * sizeof(int);
    int*   basep = (int*)w;                      w += (size_t)NN * sizeof(int);
    int*   cursor= (int*)w;                      w += (size_t)NN * sizeof(int);
    int*   bsum  = (int*)w;                      w += 256 * sizeof(int);
    int2*  cpair = (int2*)w;                     w += (size_t)EE * sizeof(int2);
    unsigned* ceid = (unsigned*)w;               w += (size_t)EE * sizeof(unsigned);

    hipMemsetAsync(counts, 0, (size_t)NN * sizeof(int), stream);

    int blk = 256;
    hist_kernel<<<(EE + blk - 1) / blk, blk, 0, stream>>>(erow, counts);
    scanA<<<NBLK, SCAN_BLK, 0, stream>>>(counts, basep, bsum);
    scanB<<<1, SCAN_BLK, 0, stream>>>(bsum);
    scanC<<<NBLK, SCAN_BLK, 0, stream>>>(basep, bsum, cursor);
    scatter_eid<<<(EE + blk - 1) / blk, blk, 0, stream>>>(erow, basep, cursor, ceid);
    rowsort_fill<<<(NN + 3) / 4, blk, 0, stream>>>(basep, counts, ceid,
                                                   ecol, evals, cpair);

    float* cl = out + (size_t)NN * DD;   // out[N:2N] = cl region
    int grd = (NN + 15) / 16;            // 16 rows per 256-thread block
    const int IMAX = 0x7FFFFFFF;

    // k=0: gather from split (ue, ie); ego -> cl region only
    spmm_fused<<<grd, blk, 0, stream>>>(basep, counts, cpair,
                                        ue, ie, UCNT,
                                        noise + (size_t)0 * NN * DD,
                                        cl, nullptr, nullptr, nullptr, 0);
    // k=1: gather from cl region; ego -> x_a only
    spmm_fused<<<grd, blk, 0, stream>>>(basep, counts, cpair,
                                        cl, nullptr, IMAX,
                                        noise + (size_t)1 * NN * DD,
                                        x_a, nullptr, nullptr, nullptr, 1);
    // k=2: gather from x_a; out[0:N] = (cl + x_a + ego)/3
    spmm_fused<<<grd, blk, 0, stream>>>(basep, counts, cpair,
                                        x_a, nullptr, IMAX,
                                        noise + (size_t)2 * NN * DD,
                                        nullptr, cl, x_a, out, 2);
}